// Round 4
// baseline (1932.615 us; speedup 1.0000x reference)
//
#include <hip/hip_runtime.h>

typedef unsigned short u16;
typedef short s16x8 __attribute__((ext_vector_type(8)));
typedef float f32x4 __attribute__((ext_vector_type(4)));

#define LAYERS   64
#define M_NODES  2048
#define DIM      128
#define FD       512
#define CHUNK    16
#define NBLK     128     // M_NODES / CHUNK; 128 blocks <= 256 CUs -> co-resident
#define TPB      512     // 8 waves; wave wv owns hidden dims [wv*16, wv*16+16)
#define XPAD     136     // 128 + 8 pad u16 (16B-aligned rows)

__device__ __forceinline__ u16 f2bf(float f) {
    union { float f; unsigned int i; } v; v.f = f;
    unsigned int r = (v.i + 0x7FFFu + ((v.i >> 16) & 1u)) >> 16;
    return (u16)r;
}
__device__ __forceinline__ float sigm(float x) {
    return __builtin_amdgcn_rcpf(1.0f + __builtin_exp2f(-1.44269504f * x));
}
__device__ __forceinline__ float tanh_f(float x) {
    float ax = __builtin_fabsf(x);
    float t  = __builtin_exp2f(-2.88539008f * ax);   // exp(-2|x|)
    float r  = (1.0f - t) * __builtin_amdgcn_rcpf(1.0f + t);
    return __builtin_copysignf(r, x);
}

// ---------------- layer 0: emb[m] = basic_table[basic_names[m]]  (fp32 copy) ----------------
__global__ void l0_kernel(const int* __restrict__ names, const float* __restrict__ table,
                          float* __restrict__ emb) {
    int v = blockIdx.x * blockDim.x + threadIdx.x;      // 2048 rows * 32 float4
    if (v >= M_NODES * (DIM / 4)) return;
    int row = v >> 5, c = v & 31;
    const float4* src = (const float4*)(table + (size_t)names[row] * DIM);
    ((float4*)(emb + (size_t)row * DIM))[c] = src[c];
}

// ------------- repack W_m,U_m,W_s,U_s (fp32) into bf16 MFMA B-fragments in d_ws -------------
__global__ void repack_kernel(const float* __restrict__ Wm, const float* __restrict__ Um,
                              const float* __restrict__ Ws, const float* __restrict__ Us,
                              u16* __restrict__ packed) {
    int t = blockIdx.x * blockDim.x + threadIdx.x;      // 4*4*32*64 = 32768 threads
    if (t >= 4 * 4 * 32 * 64) return;
    int lane = t & 63, ntg = (t >> 6) & 31, kc = (t >> 11) & 3, mat = t >> 13;
    const float* B = (mat == 0) ? Wm : (mat == 1) ? Um : (mat == 2) ? Ws : Us;
    int q = lane >> 4, nl = lane & 15;
    int kb = kc * 32 + q * 8;
    int n  = ntg * 16 + nl;
    u16* dst = packed + ((((size_t)mat * 4 + kc) * 32 + ntg) * 64 + lane) * 8;
    #pragma unroll
    for (int j = 0; j < 8; j++) dst[j] = f2bf(B[(size_t)(kb + j) * FD + n]);
}

__global__ void init_bar(int* bar) { if (threadIdx.x < 2) bar[threadIdx.x] = 0; }

__device__ __forceinline__ s16x8 load_bfrag(const u16* __restrict__ packed,
                                            int mat, int kc, int ntile, int lane) {
    return *(const s16x8*)(packed + ((((size_t)mat * 4 + kc) * 32 + ntile) * 64 + lane) * 8);
}

// One LSTM phase. Gate-local N split: wave wv's lanes end each step holding all 4
// gate pre-activations for (m = q*4+r2, d = wv*16+nl) -> gates are register-only.
// One __syncthreads per step (h transpose via double-buffered hbuf); t=0 skips h@U.
template<int NSTEPS>
__device__ __forceinline__ void lstm_phase(
    const u16* __restrict__ packed, const int matW, const int matU,
    const float* __restrict__ bz /*4 regs*/, const int* slots,
    u16 (*xs)[CHUNK][XPAD], u16 (*hbuf)[CHUNK][XPAD], const u16* empty_s,
    float* __restrict__ out /* emb row base, or null -> write h_m to xs[0] */,
    const int wv, const int lane)
{
    const int q = lane >> 4, nl = lane & 15;
    const int d = wv * 16 + nl;
    s16x8 wf[4][4], uf[4][4];
    #pragma unroll
    for (int kc = 0; kc < 4; kc++)
        #pragma unroll
        for (int g = 0; g < 4; g++) {
            wf[kc][g] = load_bfrag(packed, matW, kc, g * 8 + wv, lane);
            uf[kc][g] = load_bfrag(packed, matU, kc, g * 8 + wv, lane);
        }
    float cc[4] = {0.f, 0.f, 0.f, 0.f};
    #pragma unroll
    for (int t = 0; t < NSTEPS; t++) {
        const int s = slots[t];                 // compile-time after unroll
        f32x4 acc[4];
        #pragma unroll
        for (int g = 0; g < 4; g++) acc[g] = (f32x4){0.f, 0.f, 0.f, 0.f};
        #pragma unroll
        for (int kc = 0; kc < 4; kc++) {        // x_t @ W
            s16x8 a = (s < 0) ? *(const s16x8*)(empty_s + kc * 32 + q * 8)
                              : *(const s16x8*)(&xs[s][nl][kc * 32 + q * 8]);
            #pragma unroll
            for (int g = 0; g < 4; g++)
                acc[g] = __builtin_amdgcn_mfma_f32_16x16x32_bf16(a, wf[kc][g], acc[g], 0, 0, 0);
        }
        if (t > 0) {                            // h_{t-1} @ U (t=0: h=0)
            __syncthreads();
            #pragma unroll
            for (int kc = 0; kc < 4; kc++) {
                s16x8 a = *(const s16x8*)(&hbuf[(t - 1) & 1][nl][kc * 32 + q * 8]);
                #pragma unroll
                for (int g = 0; g < 4; g++)
                    acc[g] = __builtin_amdgcn_mfma_f32_16x16x32_bf16(a, uf[kc][g], acc[g], 0, 0, 0);
            }
        }
        const bool last = (t == NSTEPS - 1);
        #pragma unroll
        for (int r2 = 0; r2 < 4; r2++) {        // lane owns (m = q*4+r2, d)
            int m = q * 4 + r2;
            float zi = acc[0][r2] + bz[0];
            float zf = acc[1][r2] + bz[1];
            float zg = acc[2][r2] + bz[2];
            float zo = acc[3][r2] + bz[3];
            float c  = sigm(zf) * cc[r2] + sigm(zi) * tanh_f(zg);
            cc[r2] = c;
            float h  = sigm(zo) * tanh_f(c);
            if (!last)            hbuf[t & 1][m][d] = f2bf(h);
            else if (out == nullptr) xs[0][m][d] = f2bf(h);            // h_m -> seq_s[2]
            else                  out[(size_t)m * DIM + d] = h;        // fp32 layer output
        }
    }
}

// ----------------------- persistent cooperative kernel: layers 1..63 -----------------------
__global__ __launch_bounds__(TPB, 2) void persist_kernel(
    float* __restrict__ emb, const int* __restrict__ prop_ids, const int* __restrict__ super_ids,
    const float* __restrict__ bm, const float* __restrict__ bs,
    const float* __restrict__ empty, const u16* __restrict__ packed, int* bar) {

    __shared__ __align__(16) u16  xs[6][CHUNK][XPAD];   // 0..3 props (0 reused for h_m), 4..5 supers
    __shared__ __align__(16) u16  hbuf[2][CHUNK][XPAD];
    __shared__ __align__(16) u16  empty_s[XPAD];

    const int tid  = threadIdx.x;
    const int g0   = blockIdx.x * CHUNK;
    const int wv   = tid >> 6;
    const int lane = tid & 63;
    const int d    = wv * 16 + (lane & 15);

    if (tid < DIM) empty_s[tid] = f2bf(empty[tid]);
    float bzm[4], bzs[4];
    #pragma unroll
    for (int g = 0; g < 4; g++) { bzm[g] = bm[g * 128 + d]; bzs[g] = bs[g * 128 + d]; }

    const int c32  = tid & 31;          // float4 column within row
    const int node = tid >> 5;          // 0..15

    #pragma unroll 1
    for (int l = 1; l < LAYERS; l++) {
        // ---- gather: 96 rows (16 nodes x (4 props + 2 supers)) fp32 -> bf16 LDS ----
        #pragma unroll
        for (int k = 0; k < 6; k++) {   // slot = k (props 0..3, supers 4..5), node = tid>>5
            int idx = (k < 4) ? prop_ids [((size_t)l * M_NODES + g0 + node) * 4 + k]
                              : super_ids[((size_t)l * M_NODES + g0 + node) * 2 + (k - 4)];
            float4 v = ((const float4*)(emb + (size_t)idx * DIM))[c32];
            u16* dst = &xs[k][node][c32 * 4];
            dst[0] = f2bf(v.x); dst[1] = f2bf(v.y); dst[2] = f2bf(v.z); dst[3] = f2bf(v.w);
        }
        __syncthreads();

        const int slots_m[5] = {-1, 0, 1, 2, 3};    // [empty, prop0..3]
        lstm_phase<5>(packed, 0, 1, bzm, slots_m, xs, hbuf, empty_s, nullptr, wv, lane);
        const int slots_s[3] = {4, 5, 0};           // [sup0, sup1, h_m]
        lstm_phase<3>(packed, 2, 3, bzs, slots_s, xs, hbuf, empty_s,
                      emb + ((size_t)l * M_NODES + g0) * DIM, wv, lane);

        // ---- grid barrier: make this layer's emb rows visible to all blocks ----
        if (l < LAYERS - 1) {
            __syncthreads();
            if (tid == 0) {
                __builtin_amdgcn_fence(__ATOMIC_RELEASE, "agent");
                __hip_atomic_fetch_add(bar, 1, __ATOMIC_RELAXED, __HIP_MEMORY_SCOPE_AGENT);
                const int target = l * NBLK;
                while (__hip_atomic_load(bar, __ATOMIC_RELAXED, __HIP_MEMORY_SCOPE_AGENT) < target)
                    __builtin_amdgcn_s_sleep(2);
                __builtin_amdgcn_fence(__ATOMIC_ACQUIRE, "agent");
            }
            __syncthreads();
        }
    }
}

// --------------------- fallback (ws too small): per-layer, direct weight loads ---------------------
__global__ __launch_bounds__(TPB, 2) void layer_fallback(
    float* __restrict__ emb, const int* __restrict__ prop_ids, const int* __restrict__ super_ids,
    const float* __restrict__ Wm, const float* __restrict__ Um, const float* __restrict__ bm,
    const float* __restrict__ Ws, const float* __restrict__ Us, const float* __restrict__ bs,
    const float* __restrict__ empty, int l) {

    __shared__ __align__(16) u16  xs[6][CHUNK][XPAD];
    __shared__ __align__(16) u16  hbuf[2][CHUNK][XPAD];
    __shared__ __align__(16) u16  empty_s[XPAD];

    const int tid  = threadIdx.x;
    const int g0   = blockIdx.x * CHUNK;
    const int wv   = tid >> 6, lane = tid & 63;
    const int q    = lane >> 4, nl = lane & 15;
    const int d    = wv * 16 + nl;
    const int c32  = tid & 31, node = tid >> 5;

    if (tid < DIM) empty_s[tid] = f2bf(empty[tid]);
    #pragma unroll
    for (int k = 0; k < 6; k++) {
        int idx = (k < 4) ? prop_ids [((size_t)l * M_NODES + g0 + node) * 4 + k]
                          : super_ids[((size_t)l * M_NODES + g0 + node) * 2 + (k - 4)];
        float4 v = ((const float4*)(emb + (size_t)idx * DIM))[c32];
        u16* dst = &xs[k][node][c32 * 4];
        dst[0] = f2bf(v.x); dst[1] = f2bf(v.y); dst[2] = f2bf(v.z); dst[3] = f2bf(v.w);
    }
    __syncthreads();

    auto direct = [&](const float* B, int kc, int g) -> s16x8 {
        int kb = kc * 32 + q * 8, n = g * 128 + d;
        s16x8 f;
        #pragma unroll
        for (int j = 0; j < 8; j++) f[j] = (short)f2bf(B[(size_t)(kb + j) * FD + n]);
        return f;
    };
    auto run = [&](const float* W, const float* U, const float* bias,
                   int nsteps, const int* slots, float* out) {
        s16x8 wf[4][4], uf[4][4];
        #pragma unroll
        for (int kc = 0; kc < 4; kc++)
            #pragma unroll
            for (int g = 0; g < 4; g++) { wf[kc][g] = direct(W, kc, g); uf[kc][g] = direct(U, kc, g); }
        float bz[4];
        #pragma unroll
        for (int g = 0; g < 4; g++) bz[g] = bias[g * 128 + d];
        float cc[4] = {0.f, 0.f, 0.f, 0.f};
        #pragma unroll 1
        for (int t = 0; t < nsteps; t++) {
            int s = slots[t];
            f32x4 acc[4];
            #pragma unroll
            for (int g = 0; g < 4; g++) acc[g] = (f32x4){0.f, 0.f, 0.f, 0.f};
            #pragma unroll
            for (int kc = 0; kc < 4; kc++) {
                s16x8 a = (s < 0) ? *(const s16x8*)(empty_s + kc * 32 + q * 8)
                                  : *(const s16x8*)(&xs[s][nl][kc * 32 + q * 8]);
                #pragma unroll
                for (int g = 0; g < 4; g++)
                    acc[g] = __builtin_amdgcn_mfma_f32_16x16x32_bf16(a, wf[kc][g], acc[g], 0, 0, 0);
            }
            if (t > 0) {
                __syncthreads();
                #pragma unroll
                for (int kc = 0; kc < 4; kc++) {
                    s16x8 a = *(const s16x8*)(&hbuf[(t - 1) & 1][nl][kc * 32 + q * 8]);
                    #pragma unroll
                    for (int g = 0; g < 4; g++)
                        acc[g] = __builtin_amdgcn_mfma_f32_16x16x32_bf16(a, uf[kc][g], acc[g], 0, 0, 0);
                }
            }
            bool last = (t == nsteps - 1);
            #pragma unroll
            for (int r2 = 0; r2 < 4; r2++) {
                int m = q * 4 + r2;
                float zi = acc[0][r2] + bz[0];
                float zf = acc[1][r2] + bz[1];
                float zg = acc[2][r2] + bz[2];
                float zo = acc[3][r2] + bz[3];
                float c  = sigm(zf) * cc[r2] + sigm(zi) * tanh_f(zg);
                cc[r2] = c;
                float h  = sigm(zo) * tanh_f(c);
                if (!last)               hbuf[t & 1][m][d] = f2bf(h);
                else if (out == nullptr) xs[0][m][d] = f2bf(h);
                else                     out[(size_t)m * DIM + d] = h;
            }
        }
    };
    const int slots_m[5] = {-1, 0, 1, 2, 3};
    run(Wm, Um, bm, 5, slots_m, nullptr);
    const int slots_s[3] = {4, 5, 0};
    run(Ws, Us, bs, 3, slots_s, emb + ((size_t)l * M_NODES + g0) * DIM);
}

extern "C" void kernel_launch(void* const* d_in, const int* in_sizes, int n_in,
                              void* d_out, int out_size, void* d_ws, size_t ws_size,
                              hipStream_t stream) {
    const int*   names = (const int*)d_in[0];
    const int*   pids  = (const int*)d_in[1];
    const int*   sids  = (const int*)d_in[2];
    const float* table = (const float*)d_in[3];
    const float* Wm    = (const float*)d_in[4];
    const float* Um    = (const float*)d_in[5];
    const float* bm    = (const float*)d_in[6];
    const float* Ws    = (const float*)d_in[7];
    const float* Us    = (const float*)d_in[8];
    const float* bs    = (const float*)d_in[9];
    const float* empt  = (const float*)d_in[10];
    float* emb  = (float*)d_out;

    const size_t packed_bytes = (size_t)4 * 4 * 32 * 64 * 8 * sizeof(u16);  // 512 KB
    u16* packed = (u16*)d_ws;
    int* bar    = (int*)((char*)d_ws + packed_bytes);

    l0_kernel<<<256, 256, 0, stream>>>(names, table, emb);

    if (ws_size >= packed_bytes + 256) {
        repack_kernel<<<128, 256, 0, stream>>>(Wm, Um, Ws, Us, packed);
        init_bar<<<1, 64, 0, stream>>>(bar);
        void* args[] = {(void*)&emb, (void*)&pids, (void*)&sids, (void*)&bm, (void*)&bs,
                        (void*)&empt, (void*)&packed, (void*)&bar};
        hipLaunchCooperativeKernel((const void*)persist_kernel, dim3(NBLK), dim3(TPB),
                                   args, 0, stream);
    } else {
        for (int l = 1; l < LAYERS; l++)
            layer_fallback<<<NBLK, TPB, 0, stream>>>(emb, pids, sids, Wm, Um, bm,
                                                     Ws, Us, bs, empt, l);
    }
}

// Round 5
// 1729.591 us; speedup vs baseline: 1.1174x; 1.1174x over previous
//
#include <hip/hip_runtime.h>

typedef unsigned short u16;
typedef short s16x8 __attribute__((ext_vector_type(8)));
typedef float f32x4 __attribute__((ext_vector_type(4)));

#define LAYERS   64
#define M_NODES  2048
#define DIM      128
#define FD       512
#define CHUNK    16
#define NBLK     128     // M_NODES / CHUNK; co-resident on 256 CUs
#define TPB      512     // 8 waves; wave wv owns hidden dims [wv*16, wv*16+16)
#define XPAD     136     // 128 + 8 pad u16 (16B-aligned rows)

__device__ __forceinline__ u16 f2bf(float f) {
    union { float f; unsigned int i; } v; v.f = f;
    unsigned int r = (v.i + 0x7FFFu + ((v.i >> 16) & 1u)) >> 16;
    return (u16)r;
}
__device__ __forceinline__ float i2f(int x) {
    union { int i; float f; } v; v.i = x; return v.f;
}
__device__ __forceinline__ int f2i(float x) {
    union { float f; int i; } v; v.f = x; return v.i;
}
__device__ __forceinline__ float sigm(float x) {
    return __builtin_amdgcn_rcpf(1.0f + __builtin_exp2f(-1.44269504f * x));
}
__device__ __forceinline__ float tanh_f(float x) {
    float ax = __builtin_fabsf(x);
    float t  = __builtin_exp2f(-2.88539008f * ax);   // exp(-2|x|)
    float r  = (1.0f - t) * __builtin_amdgcn_rcpf(1.0f + t);
    return __builtin_copysignf(r, x);
}

// ---------------- layer 0: emb[m] = basic_table[basic_names[m]]  (fp32 copy) ----------------
__global__ void l0_kernel(const int* __restrict__ names, const float* __restrict__ table,
                          float* __restrict__ emb) {
    int v = blockIdx.x * blockDim.x + threadIdx.x;      // 2048 rows * 32 float4
    if (v >= M_NODES * (DIM / 4)) return;
    int row = v >> 5, c = v & 31;
    const float4* src = (const float4*)(table + (size_t)names[row] * DIM);
    ((float4*)(emb + (size_t)row * DIM))[c] = src[c];
}

// ------------- repack W_m,U_m,W_s,U_s (fp32) into bf16 MFMA B-fragments in d_ws -------------
__global__ void repack_kernel(const float* __restrict__ Wm, const float* __restrict__ Um,
                              const float* __restrict__ Ws, const float* __restrict__ Us,
                              u16* __restrict__ packed) {
    int t = blockIdx.x * blockDim.x + threadIdx.x;      // 4*4*32*64 = 32768 threads
    if (t >= 4 * 4 * 32 * 64) return;
    int lane = t & 63, ntg = (t >> 6) & 31, kc = (t >> 11) & 3, mat = t >> 13;
    const float* B = (mat == 0) ? Wm : (mat == 1) ? Um : (mat == 2) ? Ws : Us;
    int q = lane >> 4, nl = lane & 15;
    int kb = kc * 32 + q * 8;
    int n  = ntg * 16 + nl;
    u16* dst = packed + ((((size_t)mat * 4 + kc) * 32 + ntg) * 64 + lane) * 8;
    #pragma unroll
    for (int j = 0; j < 8; j++) dst[j] = f2bf(B[(size_t)(kb + j) * FD + n]);
}

__global__ void init_bar(int* bar) { if (threadIdx.x < 2) bar[threadIdx.x] = 0; }

__device__ __forceinline__ s16x8 load_bfrag(const u16* __restrict__ packed,
                                            int mat, int kc, int ntile, int lane) {
    return *(const s16x8*)(packed + ((((size_t)mat * 4 + kc) * 32 + ntile) * 64 + lane) * 8);
}
// accumulate one 16x128 A-tile (LDS) against resident B-fragments
__device__ __forceinline__ void acc_tile(f32x4 acc[4], const u16* __restrict__ X,
                                         const s16x8 f[4][4], int nl, int q) {
    #pragma unroll
    for (int kc = 0; kc < 4; kc++) {
        s16x8 a = *(const s16x8*)(X + (size_t)nl * XPAD + kc * 32 + q * 8);
        #pragma unroll
        for (int g = 0; g < 4; g++)
            acc[g] = __builtin_amdgcn_mfma_f32_16x16x32_bf16(a, f[kc][g], acc[g], 0, 0, 0);
    }
}

// ----------------------- persistent cooperative kernel: layers 1..63 -----------------------
// Coherence design: emb is the ONLY cross-block data. All emb loads/stores are agent-scope
// relaxed atomics (sc0 sc1 -> bypass L1/L2, L3 is the coherence point), so the grid barrier
// needs NO acquire/release cache maintenance -> packed weights stay L2-resident all kernel.
__global__ __launch_bounds__(TPB, 2) void persist_kernel(
    float* __restrict__ emb, const int* __restrict__ prop_ids, const int* __restrict__ super_ids,
    const float* __restrict__ bm, const float* __restrict__ bs,
    const float* __restrict__ empty, const u16* __restrict__ packed, int* bar) {

    __shared__ __align__(16) u16  xs[6][CHUNK][XPAD];   // 0..3 props (0 reused for h_m), 4..5 supers
    __shared__ __align__(16) u16  hbuf[2][CHUNK][XPAD];
    __shared__ __align__(16) u16  h0buf[CHUNK][XPAD];   // layer-invariant h after LSTM_m t=0
    __shared__ __align__(16) u16  empty_s[XPAD];

    const int tid  = threadIdx.x;
    const int g0   = blockIdx.x * CHUNK;
    const int wv   = tid >> 6;
    const int lane = tid & 63;
    const int q    = lane >> 4, nl = lane & 15;
    const int d    = wv * 16 + nl;
    const int c32  = tid & 31;          // float4-group column within a row
    const int node = tid >> 5;          // 0..15

    const int* embi = (const int*)emb;
    int*       embo = (int*)emb;

    if (tid < DIM) empty_s[tid] = f2bf(empty[tid]);
    float bzm[4], bzs[4];
    #pragma unroll
    for (int g = 0; g < 4; g++) { bzm[g] = bm[g * 128 + d]; bzs[g] = bs[g * 128 + d]; }
    __syncthreads();

    // ---- precompute LSTM_m t=0 (x=empty, h=0): identical for every node & layer ----
    float c0;
    {
        s16x8 wfm[4][4];
        #pragma unroll
        for (int kc = 0; kc < 4; kc++)
            #pragma unroll
            for (int g = 0; g < 4; g++) wfm[kc][g] = load_bfrag(packed, 0, kc, g * 8 + wv, lane);
        f32x4 acc[4];
        #pragma unroll
        for (int g = 0; g < 4; g++) acc[g] = (f32x4){0.f, 0.f, 0.f, 0.f};
        #pragma unroll
        for (int kc = 0; kc < 4; kc++) {
            s16x8 a = *(const s16x8*)(&empty_s[kc * 32 + q * 8]);   // all A-rows identical
            #pragma unroll
            for (int g = 0; g < 4; g++)
                acc[g] = __builtin_amdgcn_mfma_f32_16x16x32_bf16(a, wfm[kc][g], acc[g], 0, 0, 0);
        }
        float zi = acc[0][0] + bzm[0], zf = acc[1][0] + bzm[1];
        float zg = acc[2][0] + bzm[2], zo = acc[3][0] + bzm[3];
        c0 = sigm(zi) * tanh_f(zg);            // c_prev = 0
        u16 h0b = f2bf(sigm(zo) * tanh_f(c0));
        #pragma unroll
        for (int r2 = 0; r2 < 4; r2++) h0buf[q * 4 + r2][d] = h0b;
    }
    __syncthreads();

    #pragma unroll 1
    for (int l = 1; l < LAYERS; l++) {
        // ---- gather: 96 rows, agent-coherent dword loads -> bf16 LDS ----
        #pragma unroll
        for (int k = 0; k < 6; k++) {
            int idx = (k < 4) ? prop_ids [((size_t)l * M_NODES + g0 + node) * 4 + k]
                              : super_ids[((size_t)l * M_NODES + g0 + node) * 2 + (k - 4)];
            const int* src = embi + (size_t)idx * DIM + c32 * 4;
            int w0 = __hip_atomic_load(src + 0, __ATOMIC_RELAXED, __HIP_MEMORY_SCOPE_AGENT);
            int w1 = __hip_atomic_load(src + 1, __ATOMIC_RELAXED, __HIP_MEMORY_SCOPE_AGENT);
            int w2 = __hip_atomic_load(src + 2, __ATOMIC_RELAXED, __HIP_MEMORY_SCOPE_AGENT);
            int w3 = __hip_atomic_load(src + 3, __ATOMIC_RELAXED, __HIP_MEMORY_SCOPE_AGENT);
            u16* dst = &xs[k][node][c32 * 4];
            dst[0] = f2bf(i2f(w0)); dst[1] = f2bf(i2f(w1));
            dst[2] = f2bf(i2f(w2)); dst[3] = f2bf(i2f(w3));
        }
        __syncthreads();

        // ---- phase 1: LSTM_m steps t=1..4 (t=0 hoisted) ----
        {
            s16x8 wf[4][4], uf[4][4];
            #pragma unroll
            for (int kc = 0; kc < 4; kc++)
                #pragma unroll
                for (int g = 0; g < 4; g++) {
                    wf[kc][g] = load_bfrag(packed, 0, kc, g * 8 + wv, lane);
                    uf[kc][g] = load_bfrag(packed, 1, kc, g * 8 + wv, lane);
                }
            float cc[4] = {c0, c0, c0, c0};
            #pragma unroll
            for (int t = 1; t <= 4; t++) {
                if (t > 1) __syncthreads();                  // h_{t-1} visible
                const u16* hp = (t == 1) ? &h0buf[0][0] : &hbuf[(t - 1) & 1][0][0];
                f32x4 acc[4];
                #pragma unroll
                for (int g = 0; g < 4; g++) acc[g] = (f32x4){0.f, 0.f, 0.f, 0.f};
                acc_tile(acc, &xs[t - 1][0][0], wf, nl, q);  // x_t = prop[t-1]
                acc_tile(acc, hp, uf, nl, q);
                #pragma unroll
                for (int r2 = 0; r2 < 4; r2++) {
                    int m = q * 4 + r2;
                    float zi = acc[0][r2] + bzm[0], zf = acc[1][r2] + bzm[1];
                    float zg = acc[2][r2] + bzm[2], zo = acc[3][r2] + bzm[3];
                    float c  = sigm(zf) * cc[r2] + sigm(zi) * tanh_f(zg);
                    cc[r2] = c;
                    float h  = sigm(zo) * tanh_f(c);
                    if (t < 4) hbuf[t & 1][m][d] = f2bf(h);
                    else       xs[0][m][d] = f2bf(h);        // h_m -> seq_s[2]
                }
            }
        }
        // ---- phase 2: LSTM_s steps t=0..2 over [sup0, sup1, h_m] ----
        {
            s16x8 wf[4][4], uf[4][4];
            #pragma unroll
            for (int kc = 0; kc < 4; kc++)
                #pragma unroll
                for (int g = 0; g < 4; g++) {
                    wf[kc][g] = load_bfrag(packed, 2, kc, g * 8 + wv, lane);
                    uf[kc][g] = load_bfrag(packed, 3, kc, g * 8 + wv, lane);
                }
            float cc[4] = {0.f, 0.f, 0.f, 0.f};
            #pragma unroll
            for (int t = 0; t < 3; t++) {
                if (t > 0) __syncthreads();                  // also covers xs[0] (h_m) before t=2
                const int xslot = (t == 0) ? 4 : (t == 1) ? 5 : 0;
                f32x4 acc[4];
                #pragma unroll
                for (int g = 0; g < 4; g++) acc[g] = (f32x4){0.f, 0.f, 0.f, 0.f};
                acc_tile(acc, &xs[xslot][0][0], wf, nl, q);
                if (t > 0) acc_tile(acc, &hbuf[(t - 1) & 1][0][0], uf, nl, q);
                #pragma unroll
                for (int r2 = 0; r2 < 4; r2++) {
                    int m = q * 4 + r2;
                    float zi = acc[0][r2] + bzs[0], zf = acc[1][r2] + bzs[1];
                    float zg = acc[2][r2] + bzs[2], zo = acc[3][r2] + bzs[3];
                    float c  = sigm(zf) * cc[r2] + sigm(zi) * tanh_f(zg);
                    cc[r2] = c;
                    float h  = sigm(zo) * tanh_f(c);
                    if (t < 2) hbuf[t & 1][m][d] = f2bf(h);
                    else       __hip_atomic_store(embo + ((size_t)l * M_NODES + g0 + m) * DIM + d,
                                                  f2i(h), __ATOMIC_RELAXED, __HIP_MEMORY_SCOPE_AGENT);
                }
            }
        }
        // ---- fence-free grid barrier (no L2 invalidate) ----
        if (l < LAYERS - 1) {
            __syncthreads();    // each wave drains vmcnt -> this block's emb stores are at L3
            if (tid == 0) {
                __hip_atomic_fetch_add(bar, 1, __ATOMIC_RELEASE, __HIP_MEMORY_SCOPE_AGENT);
                const int target = l * NBLK;
                while (__hip_atomic_load(bar, __ATOMIC_RELAXED, __HIP_MEMORY_SCOPE_AGENT) < target)
                    __builtin_amdgcn_s_sleep(2);
            }
            __asm__ __volatile__("" ::: "memory");
            __syncthreads();
        }
    }
}

// --------------------- fallback (ws too small): per-layer, direct weight loads ---------------------
__global__ __launch_bounds__(TPB, 2) void layer_fallback(
    float* __restrict__ emb, const int* __restrict__ prop_ids, const int* __restrict__ super_ids,
    const float* __restrict__ Wm, const float* __restrict__ Um, const float* __restrict__ bm,
    const float* __restrict__ Ws, const float* __restrict__ Us, const float* __restrict__ bs,
    const float* __restrict__ empty, int l) {

    __shared__ __align__(16) u16  xs[6][CHUNK][XPAD];
    __shared__ __align__(16) u16  hbuf[2][CHUNK][XPAD];
    __shared__ __align__(16) u16  empty_s[XPAD];

    const int tid  = threadIdx.x;
    const int g0   = blockIdx.x * CHUNK;
    const int wv   = tid >> 6, lane = tid & 63;
    const int q    = lane >> 4, nl = lane & 15;
    const int d    = wv * 16 + nl;
    const int c32  = tid & 31, node = tid >> 5;

    if (tid < DIM) empty_s[tid] = f2bf(empty[tid]);
    #pragma unroll
    for (int k = 0; k < 6; k++) {
        int idx = (k < 4) ? prop_ids [((size_t)l * M_NODES + g0 + node) * 4 + k]
                          : super_ids[((size_t)l * M_NODES + g0 + node) * 2 + (k - 4)];
        float4 v = ((const float4*)(emb + (size_t)idx * DIM))[c32];
        u16* dst = &xs[k][node][c32 * 4];
        dst[0] = f2bf(v.x); dst[1] = f2bf(v.y); dst[2] = f2bf(v.z); dst[3] = f2bf(v.w);
    }
    __syncthreads();

    auto direct = [&](const float* B, int kc, int g) -> s16x8 {
        int kb = kc * 32 + q * 8, n = g * 128 + d;
        s16x8 f;
        #pragma unroll
        for (int j = 0; j < 8; j++) f[j] = (short)f2bf(B[(size_t)(kb + j) * FD + n]);
        return f;
    };
    auto run = [&](const float* W, const float* U, const float* bias,
                   int nsteps, const int* slots, float* out) {
        s16x8 wf[4][4], uf[4][4];
        #pragma unroll
        for (int kc = 0; kc < 4; kc++)
            #pragma unroll
            for (int g = 0; g < 4; g++) { wf[kc][g] = direct(W, kc, g); uf[kc][g] = direct(U, kc, g); }
        float bz[4];
        #pragma unroll
        for (int g = 0; g < 4; g++) bz[g] = bias[g * 128 + d];
        float cc[4] = {0.f, 0.f, 0.f, 0.f};
        #pragma unroll 1
        for (int t = 0; t < nsteps; t++) {
            int s = slots[t];
            f32x4 acc[4];
            #pragma unroll
            for (int g = 0; g < 4; g++) acc[g] = (f32x4){0.f, 0.f, 0.f, 0.f};
            #pragma unroll
            for (int kc = 0; kc < 4; kc++) {
                s16x8 a = (s < 0) ? *(const s16x8*)(empty_s + kc * 32 + q * 8)
                                  : *(const s16x8*)(&xs[s][nl][kc * 32 + q * 8]);
                #pragma unroll
                for (int g = 0; g < 4; g++)
                    acc[g] = __builtin_amdgcn_mfma_f32_16x16x32_bf16(a, wf[kc][g], acc[g], 0, 0, 0);
            }
            if (t > 0) {
                __syncthreads();
                #pragma unroll
                for (int kc = 0; kc < 4; kc++) {
                    s16x8 a = *(const s16x8*)(&hbuf[(t - 1) & 1][nl][kc * 32 + q * 8]);
                    #pragma unroll
                    for (int g = 0; g < 4; g++)
                        acc[g] = __builtin_amdgcn_mfma_f32_16x16x32_bf16(a, uf[kc][g], acc[g], 0, 0, 0);
                }
            }
            bool last = (t == nsteps - 1);
            #pragma unroll
            for (int r2 = 0; r2 < 4; r2++) {
                int m = q * 4 + r2;
                float zi = acc[0][r2] + bz[0];
                float zf = acc[1][r2] + bz[1];
                float zg = acc[2][r2] + bz[2];
                float zo = acc[3][r2] + bz[3];
                float c  = sigm(zf) * cc[r2] + sigm(zi) * tanh_f(zg);
                cc[r2] = c;
                float h  = sigm(zo) * tanh_f(c);
                if (!last)               hbuf[t & 1][m][d] = f2bf(h);
                else if (out == nullptr) xs[0][m][d] = f2bf(h);
                else                     out[(size_t)m * DIM + d] = h;
            }
        }
    };
    const int slots_m[5] = {-1, 0, 1, 2, 3};
    run(Wm, Um, bm, 5, slots_m, nullptr);
    const int slots_s[3] = {4, 5, 0};
    run(Ws, Us, bs, 3, slots_s, emb + ((size_t)l * M_NODES + g0) * DIM);
}

extern "C" void kernel_launch(void* const* d_in, const int* in_sizes, int n_in,
                              void* d_out, int out_size, void* d_ws, size_t ws_size,
                              hipStream_t stream) {
    const int*   names = (const int*)d_in[0];
    const int*   pids  = (const int*)d_in[1];
    const int*   sids  = (const int*)d_in[2];
    const float* table = (const float*)d_in[3];
    const float* Wm    = (const float*)d_in[4];
    const float* Um    = (const float*)d_in[5];
    const float* bm    = (const float*)d_in[6];
    const float* Ws    = (const float*)d_in[7];
    const float* Us    = (const float*)d_in[8];
    const float* bs    = (const float*)d_in[9];
    const float* empt  = (const float*)d_in[10];
    float* emb  = (float*)d_out;

    const size_t packed_bytes = (size_t)4 * 4 * 32 * 64 * 8 * sizeof(u16);  // 512 KB
    u16* packed = (u16*)d_ws;
    int* bar    = (int*)((char*)d_ws + packed_bytes);

    l0_kernel<<<256, 256, 0, stream>>>(names, table, emb);

    if (ws_size >= packed_bytes + 256) {
        repack_kernel<<<128, 256, 0, stream>>>(Wm, Um, Ws, Us, packed);
        init_bar<<<1, 64, 0, stream>>>(bar);
        void* args[] = {(void*)&emb, (void*)&pids, (void*)&sids, (void*)&bm, (void*)&bs,
                        (void*)&empt, (void*)&packed, (void*)&bar};
        hipLaunchCooperativeKernel((const void*)persist_kernel, dim3(NBLK), dim3(TPB),
                                   args, 0, stream);
    } else {
        for (int l = 1; l < LAYERS; l++)
            layer_fallback<<<NBLK, TPB, 0, stream>>>(emb, pids, sids, Wm, Um, bm,
                                                     Ws, Us, bs, empt, l);
    }
}

// Round 6
// 1674.569 us; speedup vs baseline: 1.1541x; 1.0329x over previous
//
#include <hip/hip_runtime.h>

typedef unsigned short u16;
typedef short s16x8 __attribute__((ext_vector_type(8)));
typedef float f32x4 __attribute__((ext_vector_type(4)));

#define LAYERS   64
#define M_NODES  2048
#define DIM      128
#define FD       512
#define CHUNK    16
#define NBLK     128     // M_NODES / CHUNK
#define TPB      512     // 8 waves; wave wv owns hidden dims [wv*16, wv*16+16)
#define XPAD     136     // 128 + 8 pad u16 (16B-aligned rows)

__device__ __forceinline__ u16 f2bf(float f) {
    union { float f; unsigned int i; } v; v.f = f;
    unsigned int r = (v.i + 0x7FFFu + ((v.i >> 16) & 1u)) >> 16;
    return (u16)r;
}
__device__ __forceinline__ float i2f(int x) {
    union { int i; float f; } v; v.i = x; return v.f;
}
__device__ __forceinline__ int f2i(float x) {
    union { float f; int i; } v; v.f = x; return v.i;
}
__device__ __forceinline__ float sigm(float x) {
    return __builtin_amdgcn_rcpf(1.0f + __builtin_exp2f(-1.44269504f * x));
}
__device__ __forceinline__ float tanh_f(float x) {
    float ax = __builtin_fabsf(x);
    float t  = __builtin_exp2f(-2.88539008f * ax);   // exp(-2|x|)
    float r  = (1.0f - t) * __builtin_amdgcn_rcpf(1.0f + t);
    return __builtin_copysignf(r, x);
}

// ---------------- layer 0: emb[m] = basic_table[basic_names[m]]  (fp32 copy) ----------------
__global__ void l0_kernel(const int* __restrict__ names, const float* __restrict__ table,
                          float* __restrict__ emb) {
    int v = blockIdx.x * blockDim.x + threadIdx.x;      // 2048 rows * 32 float4
    if (v >= M_NODES * (DIM / 4)) return;
    int row = v >> 5, c = v & 31;
    const float4* src = (const float4*)(table + (size_t)names[row] * DIM);
    ((float4*)(emb + (size_t)row * DIM))[c] = src[c];
}

// ------------- repack W_m,U_m,W_s,U_s (fp32) into bf16 MFMA B-fragments in d_ws -------------
__global__ void repack_kernel(const float* __restrict__ Wm, const float* __restrict__ Um,
                              const float* __restrict__ Ws, const float* __restrict__ Us,
                              u16* __restrict__ packed) {
    int t = blockIdx.x * blockDim.x + threadIdx.x;      // 4*4*32*64 = 32768 threads
    if (t >= 4 * 4 * 32 * 64) return;
    int lane = t & 63, ntg = (t >> 6) & 31, kc = (t >> 11) & 3, mat = t >> 13;
    const float* B = (mat == 0) ? Wm : (mat == 1) ? Um : (mat == 2) ? Ws : Us;
    int q = lane >> 4, nl = lane & 15;
    int kb = kc * 32 + q * 8;
    int n  = ntg * 16 + nl;
    u16* dst = packed + ((((size_t)mat * 4 + kc) * 32 + ntg) * 64 + lane) * 8;
    #pragma unroll
    for (int j = 0; j < 8; j++) dst[j] = f2bf(B[(size_t)(kb + j) * FD + n]);
}

__global__ void init_bar(int* bar) { bar[threadIdx.x] = 0; }   // 512 threads

__device__ __forceinline__ s16x8 load_bfrag(const u16* __restrict__ packed,
                                            int mat, int kc, int ntile, int lane) {
    return *(const s16x8*)(packed + ((((size_t)mat * 4 + kc) * 32 + ntile) * 64 + lane) * 8);
}
__device__ __forceinline__ void acc_tile(f32x4 acc[4], const u16* __restrict__ X,
                                         const s16x8 f[4][4], int nl, int q) {
    #pragma unroll
    for (int kc = 0; kc < 4; kc++) {
        s16x8 a = *(const s16x8*)(X + (size_t)nl * XPAD + kc * 32 + q * 8);
        #pragma unroll
        for (int g = 0; g < 4; g++)
            acc[g] = __builtin_amdgcn_mfma_f32_16x16x32_bf16(a, f[kc][g], acc[g], 0, 0, 0);
    }
}

// ----------------------- persistent cooperative kernel: layers 1..63 -----------------------
// emb is the only cross-block data; all emb traffic is agent-scope relaxed (L3-coherent,
// no cache-wide fences -> packed weights stay L2-resident). Barrier is hierarchical
// (8 group lines + 1 global). Next-layer gathers with idx < l*M prefetch under the barrier.
__global__ __launch_bounds__(TPB, 2) void persist_kernel(
    float* __restrict__ emb, const int* __restrict__ prop_ids, const int* __restrict__ super_ids,
    const float* __restrict__ bm, const float* __restrict__ bs,
    const float* __restrict__ empty, const u16* __restrict__ packed, int* bar) {

    __shared__ __align__(16) u16  xs[6][CHUNK][XPAD];   // 0..3 props (0 reused for h_m), 4..5 supers
    __shared__ __align__(16) u16  hbuf[2][CHUNK][XPAD];
    __shared__ __align__(16) u16  h0buf[CHUNK][XPAD];   // layer-invariant h after LSTM_m t=0
    __shared__ __align__(16) u16  empty_s[XPAD];
    __shared__ int                idx_s[96];            // current layer's 96 gather indices

    const int tid  = threadIdx.x;
    const int b    = blockIdx.x;
    const int g0   = b * CHUNK;
    const int wv   = tid >> 6, lane = tid & 63;
    const int q    = lane >> 4, nl = lane & 15;
    const int d    = wv * 16 + nl;
    const int w    = tid >> 7;          // gather row residue class (0..3)
    const int col  = tid & 127;         // gather dword column

    int* embi = (int*)emb;

    if (tid < DIM) empty_s[tid] = f2bf(empty[tid]);
    if (tid >= 128 && tid < 224) {      // indices for layer 1
        int r = tid - 128, k = r >> 4, node = r & 15;
        idx_s[r] = (k < 4) ? prop_ids [((size_t)M_NODES + g0 + node) * 4 + k]
                           : super_ids[((size_t)M_NODES + g0 + node) * 2 + (k - 4)];
    }
    float bzm[4], bzs[4];
    #pragma unroll
    for (int g = 0; g < 4; g++) { bzm[g] = bm[g * 128 + d]; bzs[g] = bs[g * 128 + d]; }
    __syncthreads();

    // ---- prologue prefetch for l=1 (layer 0 final via kernel ordering: all safe) ----
    int pre[24]; unsigned mask = 0;
    #pragma unroll
    for (int i = 0; i < 24; i++) {
        int idx = idx_s[i * 4 + w];
        pre[i] = __hip_atomic_load(embi + (size_t)idx * DIM + col,
                                   __ATOMIC_RELAXED, __HIP_MEMORY_SCOPE_AGENT);
    }

    // ---- LSTM_m t=0 (x=empty, h=0): identical for every node & layer (overlaps loads) ----
    float c0;
    {
        s16x8 wfm[4][4];
        #pragma unroll
        for (int kc = 0; kc < 4; kc++)
            #pragma unroll
            for (int g = 0; g < 4; g++) wfm[kc][g] = load_bfrag(packed, 0, kc, g * 8 + wv, lane);
        f32x4 acc[4];
        #pragma unroll
        for (int g = 0; g < 4; g++) acc[g] = (f32x4){0.f, 0.f, 0.f, 0.f};
        #pragma unroll
        for (int kc = 0; kc < 4; kc++) {
            s16x8 a = *(const s16x8*)(&empty_s[kc * 32 + q * 8]);   // all A-rows identical
            #pragma unroll
            for (int g = 0; g < 4; g++)
                acc[g] = __builtin_amdgcn_mfma_f32_16x16x32_bf16(a, wfm[kc][g], acc[g], 0, 0, 0);
        }
        float zi = acc[0][0] + bzm[0], zf = acc[1][0] + bzm[1];
        float zg = acc[2][0] + bzm[2], zo = acc[3][0] + bzm[3];
        c0 = sigm(zi) * tanh_f(zg);
        u16 h0b = f2bf(sigm(zo) * tanh_f(c0));
        #pragma unroll
        for (int r2 = 0; r2 < 4; r2++) h0buf[q * 4 + r2][d] = h0b;
    }
    __syncthreads();

    #pragma unroll 1
    for (int l = 1; l < LAYERS; l++) {
        // ---- stragglers (idx >= prev threshold) then fill xs from pre[] ----
        #pragma unroll
        for (int i = 0; i < 24; i++)
            if (mask & (1u << i)) {     // wave-uniform predicate
                int idx = idx_s[i * 4 + w];
                pre[i] = __hip_atomic_load(embi + (size_t)idx * DIM + col,
                                           __ATOMIC_RELAXED, __HIP_MEMORY_SCOPE_AGENT);
            }
        #pragma unroll
        for (int i = 0; i < 24; i++) {
            int row = i * 4 + w;
            xs[row >> 4][row & 15][col] = f2bf(i2f(pre[i]));
        }
        __syncthreads();

        // ---- phase 1: LSTM_m t=1..4 (t=0 hoisted); x@W issued before each step's sync ----
        {
            s16x8 wf[4][4], uf[4][4];
            #pragma unroll
            for (int kc = 0; kc < 4; kc++)
                #pragma unroll
                for (int g = 0; g < 4; g++) {
                    wf[kc][g] = load_bfrag(packed, 0, kc, g * 8 + wv, lane);
                    uf[kc][g] = load_bfrag(packed, 1, kc, g * 8 + wv, lane);
                }
            float cc[4] = {c0, c0, c0, c0};
            #pragma unroll
            for (int t = 1; t <= 4; t++) {
                f32x4 acc[4];
                #pragma unroll
                for (int g = 0; g < 4; g++) acc[g] = (f32x4){0.f, 0.f, 0.f, 0.f};
                acc_tile(acc, &xs[t - 1][0][0], wf, nl, q);   // xs static: pre-sync
                if (t > 1) __syncthreads();                   // h_{t-1} visible
                acc_tile(acc, (t == 1) ? &h0buf[0][0] : &hbuf[(t - 1) & 1][0][0], uf, nl, q);
                #pragma unroll
                for (int r2 = 0; r2 < 4; r2++) {
                    int m = q * 4 + r2;
                    float zi = acc[0][r2] + bzm[0], zf = acc[1][r2] + bzm[1];
                    float zg = acc[2][r2] + bzm[2], zo = acc[3][r2] + bzm[3];
                    float c  = sigm(zf) * cc[r2] + sigm(zi) * tanh_f(zg);
                    cc[r2] = c;
                    float h  = sigm(zo) * tanh_f(c);
                    if (t < 4) hbuf[t & 1][m][d] = f2bf(h);
                    else       xs[0][m][d] = f2bf(h);         // h_m -> seq_s[2]
                }
            }
        }
        // ---- phase 2: LSTM_s t=0..2 over [sup0, sup1, h_m] ----
        {
            s16x8 wf[4][4], uf[4][4];
            #pragma unroll
            for (int kc = 0; kc < 4; kc++)
                #pragma unroll
                for (int g = 0; g < 4; g++) {
                    wf[kc][g] = load_bfrag(packed, 2, kc, g * 8 + wv, lane);
                    uf[kc][g] = load_bfrag(packed, 3, kc, g * 8 + wv, lane);
                }
            float cc[4] = {0.f, 0.f, 0.f, 0.f};
            #pragma unroll
            for (int t = 0; t < 3; t++) {
                const int xslot = (t == 0) ? 4 : (t == 1) ? 5 : 0;
                f32x4 acc[4];
                #pragma unroll
                for (int g = 0; g < 4; g++) acc[g] = (f32x4){0.f, 0.f, 0.f, 0.f};
                acc_tile(acc, &xs[xslot][0][0], wf, nl, q);
                if (t > 0) {
                    __syncthreads();
                    acc_tile(acc, &hbuf[(t - 1) & 1][0][0], uf, nl, q);
                }
                #pragma unroll
                for (int r2 = 0; r2 < 4; r2++) {
                    int m = q * 4 + r2;
                    float zi = acc[0][r2] + bzs[0], zf = acc[1][r2] + bzs[1];
                    float zg = acc[2][r2] + bzs[2], zo = acc[3][r2] + bzs[3];
                    float c  = sigm(zf) * cc[r2] + sigm(zi) * tanh_f(zg);
                    cc[r2] = c;
                    float h  = sigm(zo) * tanh_f(c);
                    if (t < 2) hbuf[t & 1][m][d] = f2bf(h);
                    else       __hip_atomic_store(embi + ((size_t)l * M_NODES + g0 + m) * DIM + d,
                                                  f2i(h), __ATOMIC_RELAXED, __HIP_MEMORY_SCOPE_AGENT);
                }
            }
        }
        if (l == LAYERS - 1) break;

        // ---- next-layer indices, then barrier arrive + prefetch-under-wait ----
        if (tid < 96) {
            int k = tid >> 4, node = tid & 15;
            idx_s[tid] = (k < 4) ? prop_ids [((size_t)(l + 1) * M_NODES + g0 + node) * 4 + k]
                                 : super_ids[((size_t)(l + 1) * M_NODES + g0 + node) * 2 + (k - 4)];
        }
        __syncthreads();    // A: out stores drained (vmcnt0 before s_barrier); idx_s visible; xs dead
        int old = 0;
        if (tid == 0)
            old = __hip_atomic_fetch_add(bar + (b & 7) * 32, 1,
                                         __ATOMIC_RELAXED, __HIP_MEMORY_SCOPE_AGENT);
        const int thresh = l * M_NODES;     // layers 0..l-1 final since barrier l-1
        mask = 0;
        #pragma unroll
        for (int i = 0; i < 24; i++) {
            int idx = idx_s[i * 4 + w];
            if (idx < thresh)               // wave-uniform
                pre[i] = __hip_atomic_load(embi + (size_t)idx * DIM + col,
                                           __ATOMIC_RELAXED, __HIP_MEMORY_SCOPE_AGENT);
            else mask |= 1u << i;
        }
        if (tid == 0) {
            if (old == l * 16 - 1)          // last of this 16-block group
                __hip_atomic_fetch_add(bar + 8 * 32, 1,
                                       __ATOMIC_RELAXED, __HIP_MEMORY_SCOPE_AGENT);
            while (__hip_atomic_load(bar + 8 * 32, __ATOMIC_RELAXED,
                                     __HIP_MEMORY_SCOPE_AGENT) < l * 8)
                __builtin_amdgcn_s_sleep(1);
        }
        __asm__ __volatile__("" ::: "memory");
        __syncthreads();    // B: all blocks' layer-l stores visible at L3
    }
}

// --------------------- fallback (ws too small): per-layer, direct weight loads ---------------------
__global__ __launch_bounds__(TPB, 2) void layer_fallback(
    float* __restrict__ emb, const int* __restrict__ prop_ids, const int* __restrict__ super_ids,
    const float* __restrict__ Wm, const float* __restrict__ Um, const float* __restrict__ bm,
    const float* __restrict__ Ws, const float* __restrict__ Us, const float* __restrict__ bs,
    const float* __restrict__ empty, int l) {

    __shared__ __align__(16) u16  xs[6][CHUNK][XPAD];
    __shared__ __align__(16) u16  hbuf[2][CHUNK][XPAD];
    __shared__ __align__(16) u16  empty_s[XPAD];

    const int tid  = threadIdx.x;
    const int g0   = blockIdx.x * CHUNK;
    const int wv   = tid >> 6, lane = tid & 63;
    const int q    = lane >> 4, nl = lane & 15;
    const int d    = wv * 16 + nl;
    const int c32  = tid & 31, node = tid >> 5;

    if (tid < DIM) empty_s[tid] = f2bf(empty[tid]);
    #pragma unroll
    for (int k = 0; k < 6; k++) {
        int idx = (k < 4) ? prop_ids [((size_t)l * M_NODES + g0 + node) * 4 + k]
                          : super_ids[((size_t)l * M_NODES + g0 + node) * 2 + (k - 4)];
        float4 v = ((const float4*)(emb + (size_t)idx * DIM))[c32];
        u16* dst = &xs[k][node][c32 * 4];
        dst[0] = f2bf(v.x); dst[1] = f2bf(v.y); dst[2] = f2bf(v.z); dst[3] = f2bf(v.w);
    }
    __syncthreads();

    auto direct = [&](const float* B, int kc, int g) -> s16x8 {
        int kb = kc * 32 + q * 8, n = g * 128 + d;
        s16x8 f;
        #pragma unroll
        for (int j = 0; j < 8; j++) f[j] = (short)f2bf(B[(size_t)(kb + j) * FD + n]);
        return f;
    };
    auto run = [&](const float* W, const float* U, const float* bias,
                   int nsteps, const int* slots, float* out) {
        s16x8 wf[4][4], uf[4][4];
        #pragma unroll
        for (int kc = 0; kc < 4; kc++)
            #pragma unroll
            for (int g = 0; g < 4; g++) { wf[kc][g] = direct(W, kc, g); uf[kc][g] = direct(U, kc, g); }
        float bz[4];
        #pragma unroll
        for (int g = 0; g < 4; g++) bz[g] = bias[g * 128 + d];
        float cc[4] = {0.f, 0.f, 0.f, 0.f};
        #pragma unroll 1
        for (int t = 0; t < nsteps; t++) {
            int s = slots[t];
            f32x4 acc[4];
            #pragma unroll
            for (int g = 0; g < 4; g++) acc[g] = (f32x4){0.f, 0.f, 0.f, 0.f};
            #pragma unroll
            for (int kc = 0; kc < 4; kc++) {
                s16x8 a = (s < 0) ? *(const s16x8*)(empty_s + kc * 32 + q * 8)
                                  : *(const s16x8*)(&xs[s][nl][kc * 32 + q * 8]);
                #pragma unroll
                for (int g = 0; g < 4; g++)
                    acc[g] = __builtin_amdgcn_mfma_f32_16x16x32_bf16(a, wf[kc][g], acc[g], 0, 0, 0);
            }
            if (t > 0) {
                __syncthreads();
                #pragma unroll
                for (int kc = 0; kc < 4; kc++) {
                    s16x8 a = *(const s16x8*)(&hbuf[(t - 1) & 1][nl][kc * 32 + q * 8]);
                    #pragma unroll
                    for (int g = 0; g < 4; g++)
                        acc[g] = __builtin_amdgcn_mfma_f32_16x16x32_bf16(a, uf[kc][g], acc[g], 0, 0, 0);
                }
            }
            bool last = (t == nsteps - 1);
            #pragma unroll
            for (int r2 = 0; r2 < 4; r2++) {
                int m = q * 4 + r2;
                float zi = acc[0][r2] + bz[0];
                float zf = acc[1][r2] + bz[1];
                float zg = acc[2][r2] + bz[2];
                float zo = acc[3][r2] + bz[3];
                float c  = sigm(zf) * cc[r2] + sigm(zi) * tanh_f(zg);
                cc[r2] = c;
                float h  = sigm(zo) * tanh_f(c);
                if (!last)               hbuf[t & 1][m][d] = f2bf(h);
                else if (out == nullptr) xs[0][m][d] = f2bf(h);
                else                     out[(size_t)m * DIM + d] = h;
            }
        }
    };
    const int slots_m[5] = {-1, 0, 1, 2, 3};
    run(Wm, Um, bm, 5, slots_m, nullptr);
    const int slots_s[3] = {4, 5, 0};
    run(Ws, Us, bs, 3, slots_s, emb + ((size_t)l * M_NODES + g0) * DIM);
}

extern "C" void kernel_launch(void* const* d_in, const int* in_sizes, int n_in,
                              void* d_out, int out_size, void* d_ws, size_t ws_size,
                              hipStream_t stream) {
    const int*   names = (const int*)d_in[0];
    const int*   pids  = (const int*)d_in[1];
    const int*   sids  = (const int*)d_in[2];
    const float* table = (const float*)d_in[3];
    const float* Wm    = (const float*)d_in[4];
    const float* Um    = (const float*)d_in[5];
    const float* bm    = (const float*)d_in[6];
    const float* Ws    = (const float*)d_in[7];
    const float* Us    = (const float*)d_in[8];
    const float* bs    = (const float*)d_in[9];
    const float* empt  = (const float*)d_in[10];
    float* emb  = (float*)d_out;

    const size_t packed_bytes = (size_t)4 * 4 * 32 * 64 * 8 * sizeof(u16);  // 512 KB
    u16* packed = (u16*)d_ws;
    int* bar    = (int*)((char*)d_ws + packed_bytes);

    l0_kernel<<<256, 256, 0, stream>>>(names, table, emb);

    if (ws_size >= packed_bytes + 4096) {
        repack_kernel<<<128, 256, 0, stream>>>(Wm, Um, Ws, Us, packed);
        init_bar<<<1, 512, 0, stream>>>(bar);
        void* args[] = {(void*)&emb, (void*)&pids, (void*)&sids, (void*)&bm, (void*)&bs,
                        (void*)&empt, (void*)&packed, (void*)&bar};
        hipLaunchCooperativeKernel((const void*)persist_kernel, dim3(NBLK), dim3(TPB),
                                   args, 0, stream);
    } else {
        for (int l = 1; l < LAYERS; l++)
            layer_fallback<<<NBLK, TPB, 0, stream>>>(emb, pids, sids, Wm, Um, bm,
                                                     Ws, Us, bs, empt, l);
    }
}